// Round 7
// baseline (650.496 us; speedup 1.0000x reference)
//
#include <hip/hip_runtime.h>
#include <cmath>

#define L_SEQ 2048
#define BATCH 8
#define CIN 256
#define DIN 512
#define M_ROWS (BATCH * L_SEQ)  // 16384
#define NC 64                   // scan chunks
#define LC 32                   // chunk length

typedef __attribute__((ext_vector_type(8))) short short8;
typedef __attribute__((ext_vector_type(8))) unsigned short ushort8v;
typedef __attribute__((ext_vector_type(4))) float float4v;
typedef unsigned short u16;

__device__ inline u16 f2bf_rn(float x) {
  union { float f; unsigned u; } v;
  v.f = x;
  unsigned r = v.u + 0x7FFF + ((v.u >> 16) & 1);
  return (u16)(r >> 16);
}
__device__ inline float bf2f(u16 h) {
  union { unsigned u; float f; } v;
  v.u = ((unsigned)h) << 16;
  return v.f;
}

// ---------------- transpose (B,C,L) -> (B,L,C), hi/lo bf16 planes ----------------
__global__ __launch_bounds__(256) void transpose_in(const float* __restrict__ in,
                                                    u16* __restrict__ xh, u16* __restrict__ xl) {
  __shared__ float tile[32][33];
  int b = blockIdx.z;
  int l0 = blockIdx.x * 32, c0 = blockIdx.y * 32;
  int tx = threadIdx.x, ty = threadIdx.y;  // 32 x 8
#pragma unroll
  for (int k = 0; k < 4; ++k)
    tile[ty + k * 8][tx] = in[(long)(b * CIN + c0 + ty + k * 8) * L_SEQ + l0 + tx];
  __syncthreads();
#pragma unroll
  for (int k = 0; k < 4; ++k) {
    float v = tile[tx][ty + k * 8];
    long o = (long)(b * L_SEQ + l0 + ty + k * 8) * CIN + c0 + tx;
    u16 h = f2bf_rn(v);
    xh[o] = h;
    xl[o] = f2bf_rn(v - bf2f(h));
  }
}

// ---------------- weight packing to planes ----------------
__global__ __launch_bounds__(256) void split_pack(const float* __restrict__ in,
                                                  u16* __restrict__ oh, u16* __restrict__ ol,
                                                  int n) {
  int i = blockIdx.x * 256 + threadIdx.x;
  if (i < n) {
    float v = in[i];
    u16 h = f2bf_rn(v);
    oh[i] = h;
    ol[i] = f2bf_rn(v - bf2f(h));
  }
}

// Wd (640 x 512): rows 0..511 = dt_proj_w @ x_proj_w[0:16]; 512..543 = B,C rows; rest 0
__global__ __launch_bounds__(256) void build_wd(const float* __restrict__ xpw,
                                                const float* __restrict__ dtw,
                                                u16* __restrict__ Wh, u16* __restrict__ Wl) {
  int k = blockIdx.x * 256 + threadIdx.x;  // 0..511
  int n = blockIdx.y;                      // 0..639
  float v;
  if (n < 512) {
    v = 0.f;
#pragma unroll
    for (int r = 0; r < 16; ++r) v += dtw[n * 16 + r] * xpw[r * 512 + k];
  } else if (n < 544) {
    v = xpw[(16 + n - 512) * 512 + k];
  } else {
    v = 0.f;
  }
  u16 h = f2bf_rn(v);
  Wh[(long)n * 512 + k] = h;
  Wl[(long)n * 512 + k] = f2bf_rn(v - bf2f(h));
}

// W_comb (512 x 512): out_lin_w (512x256) @ out_proj_w[layer1] (256x512)
__global__ __launch_bounds__(256) void build_wcomb(const float* __restrict__ olw,
                                                   const float* __restrict__ opw,
                                                   u16* __restrict__ Wh, u16* __restrict__ Wl) {
  int d = blockIdx.x * 256 + threadIdx.x;  // 0..511
  int o = blockIdx.y;                      // 0..511
  float v = 0.f;
#pragma unroll 4
  for (int c = 0; c < 256; ++c) v += olw[o * 256 + c] * opw[(long)c * 512 + d];
  u16 h = f2bf_rn(v);
  Wh[(long)o * 512 + d] = h;
  Wl[(long)o * 512 + d] = f2bf_rn(v - bf2f(h));
}

// ---------------- bf16x3 MFMA GEMM on hi/lo planes ----------------
// C[m,n] = sum_k A[m,k]*W[n,k]; acc += AhWh + AlWh + AhWl. Staging = pure 16B copies.
// EPI 2: relu(v+bias[n]) scatter to (spk,b,c,l) fp32 (final).
// EPI 3: split fp32 store: n<512 -> C (xr, stride 512); else C2 (z, stride 512).
// EPI 4: n<512: softplus(v+bias[n]) -> C (delta, 512); 512<=n<544 -> C2 (bc, 32); else skip.
// EPI 5: hi/lo plane store -> Ch/Cl (stride 256).
#define LDSROW 40
template <int EPI>
__global__ __launch_bounds__(256) void gemm_mfma(const u16* __restrict__ Ahp,
                                                 const u16* __restrict__ Alp, int lda,
                                                 const u16* __restrict__ Whp,
                                                 const u16* __restrict__ Wlp, int K,
                                                 float* __restrict__ C, float* __restrict__ C2,
                                                 u16* __restrict__ Ch, u16* __restrict__ Cl,
                                                 const float* __restrict__ bias) {
  __shared__ u16 Ah[128 * LDSROW], Al[128 * LDSROW];
  __shared__ u16 Wh[128 * LDSROW], Wl[128 * LDSROW];
  int tid = threadIdx.x;
  int w = tid >> 6, L = tid & 63;
  int q = L >> 4, r16 = L & 15;
  int wm = (w >> 1) * 64, wn = (w & 1) * 64;
  long m0 = (long)blockIdx.y * 128, n0 = (long)blockIdx.x * 128;
  float4v acc[4][4];
#pragma unroll
  for (int i = 0; i < 4; ++i)
#pragma unroll
    for (int j = 0; j < 4; ++j) acc[i][j] = (float4v){0.f, 0.f, 0.f, 0.f};

  for (int k0 = 0; k0 < K; k0 += 32) {
#pragma unroll
    for (int r = 0; r < 2; ++r) {
      int c = tid + r * 256;  // 0..511 chunks of 8 halfs
      int row = c >> 2, ch = (c & 3) * 8;
      *(ushort8v*)&Ah[row * LDSROW + ch] = *(const ushort8v*)&Ahp[(m0 + row) * lda + k0 + ch];
      *(ushort8v*)&Al[row * LDSROW + ch] = *(const ushort8v*)&Alp[(m0 + row) * lda + k0 + ch];
      *(ushort8v*)&Wh[row * LDSROW + ch] = *(const ushort8v*)&Whp[(n0 + row) * K + k0 + ch];
      *(ushort8v*)&Wl[row * LDSROW + ch] = *(const ushort8v*)&Wlp[(n0 + row) * K + k0 + ch];
    }
    __syncthreads();
    short8 ah[4], al[4], bh[4], bl[4];
#pragma unroll
    for (int i = 0; i < 4; ++i) {
      int mr = wm + i * 16 + r16;
      ah[i] = *(const short8*)&Ah[mr * LDSROW + q * 8];
      al[i] = *(const short8*)&Al[mr * LDSROW + q * 8];
    }
#pragma unroll
    for (int j = 0; j < 4; ++j) {
      int nr = wn + j * 16 + r16;
      bh[j] = *(const short8*)&Wh[nr * LDSROW + q * 8];
      bl[j] = *(const short8*)&Wl[nr * LDSROW + q * 8];
    }
#pragma unroll
    for (int i = 0; i < 4; ++i)
#pragma unroll
      for (int j = 0; j < 4; ++j) {
        acc[i][j] = __builtin_amdgcn_mfma_f32_16x16x32_bf16(ah[i], bh[j], acc[i][j], 0, 0, 0);
        acc[i][j] = __builtin_amdgcn_mfma_f32_16x16x32_bf16(al[i], bh[j], acc[i][j], 0, 0, 0);
        acc[i][j] = __builtin_amdgcn_mfma_f32_16x16x32_bf16(ah[i], bl[j], acc[i][j], 0, 0, 0);
      }
    __syncthreads();
  }

  // D layout (16x16x32): row = q*4 + r, col = r16
#pragma unroll
  for (int i = 0; i < 4; ++i) {
    int m = (int)m0 + wm + i * 16 + q * 4;
#pragma unroll
    for (int j = 0; j < 4; ++j) {
      int n = (int)n0 + wn + j * 16 + r16;
      if (EPI == 3) {
        float* dst = (n < 512) ? C : C2;
        int nn = n & 511;
#pragma unroll
        for (int r = 0; r < 4; ++r) dst[(long)(m + r) * 512 + nn] = acc[i][j][r];
      } else if (EPI == 4) {
        if (n < 512) {
          float vb = bias[n];
#pragma unroll
          for (int r = 0; r < 4; ++r) {
            float t = acc[i][j][r] + vb;
            t = (t > 20.f) ? t : __logf(1.f + __expf(t));
            C[(long)(m + r) * 512 + n] = t;
          }
        } else if (n < 544) {
#pragma unroll
          for (int r = 0; r < 4; ++r) C2[(long)(m + r) * 32 + (n - 512)] = acc[i][j][r];
        }
      } else if (EPI == 5) {
#pragma unroll
        for (int r = 0; r < 4; ++r) {
          float v = acc[i][j][r];
          u16 h = f2bf_rn(v);
          Ch[(long)(m + r) * 256 + n] = h;
          Cl[(long)(m + r) * 256 + n] = f2bf_rn(v - bf2f(h));
        }
      } else {  // EPI == 2
        float vb = bias[n];
        int spk = n >> 8, c = n & 255;
        int b = m >> 11, l = m & 2047;
        float4v v;
#pragma unroll
        for (int r = 0; r < 4; ++r) {
          float t = acc[i][j][r] + vb;
          v[r] = t > 0.f ? t : 0.f;
        }
        *(float4v*)&C[(((long)(spk * BATCH + b)) * CIN + c) * L_SEQ + l] = v;
      }
    }
  }
}

// ---------------- depthwise causal conv(4) + bias + SiLU -> xc hi/lo planes ----------------
__global__ __launch_bounds__(256) void conv_silu(const float* __restrict__ xr,
                                                 const float* __restrict__ cw,
                                                 const float* __restrict__ cb,
                                                 u16* __restrict__ xch, u16* __restrict__ xcl) {
  int idx = blockIdx.x * 256 + threadIdx.x;
  int d = idx & 511;
  int ml = idx >> 9;
  int l = ml & 2047;
  float acc = cb[d];
  const float* w = cw + d * 4;
#pragma unroll
  for (int k = 0; k < 4; ++k) {
    int ll = l + k - 3;
    if (ll >= 0) acc += w[k] * xr[(long)(ml + k - 3) * 512 + d];
  }
  float v = acc / (1.f + __expf(-acc));
  u16 h = f2bf_rn(v);
  xch[(long)ml * 512 + d] = h;
  xcl[(long)ml * 512 + d] = f2bf_rn(v - bf2f(h));
}

// ---------------- chunked selective scan: thread per (b,d), 16 states in registers ------------
__global__ __launch_bounds__(256) void scan_pass1(const float* __restrict__ delta,
                                                  const u16* __restrict__ xch,
                                                  const u16* __restrict__ xcl,
                                                  const float* __restrict__ bc,
                                                  const float* __restrict__ A_log,
                                                  float* __restrict__ P,
                                                  float* __restrict__ Hl) {
  int b = blockIdx.z, c = blockIdx.y;
  int tid = threadIdx.x;
  int d = blockIdx.x * 256 + tid;
  __shared__ float sBC[LC][32];
  const long base = (long)b * L_SEQ + (long)c * LC;
  ((float4v*)sBC)[tid] = ((const float4v*)&bc[base * 32])[tid];
  float Aval[16];
  {
    float4v a[4];
#pragma unroll
    for (int g = 0; g < 4; ++g) a[g] = *(const float4v*)&A_log[d * 16 + g * 4];
#pragma unroll
    for (int s = 0; s < 16; ++s) Aval[s] = -__expf(a[s >> 2][s & 3]);
  }
  __syncthreads();
  float h[16];
#pragma unroll
  for (int s = 0; s < 16; ++s) h[s] = 0.f;
  float sd = 0.f;
#pragma unroll 4
  for (int t = 0; t < LC; ++t) {
    long off = (base + t) * 512 + d;
    float dlv = delta[off];
    float xv = bf2f(xch[off]) + bf2f(xcl[off]);
    float w = dlv * xv;
    sd += dlv;
    float4v Bv[4];
#pragma unroll
    for (int g = 0; g < 4; ++g) Bv[g] = *(const float4v*)&sBC[t][g * 4];
#pragma unroll
    for (int s = 0; s < 16; ++s) {
      float dA = __expf(dlv * Aval[s]);
      h[s] = dA * h[s] + w * Bv[s >> 2][s & 3];
    }
  }
  long idx = (((long)b * NC + c) * 512 + d) * 16;
#pragma unroll
  for (int g = 0; g < 4; ++g) {
    float4v pv, hv;
#pragma unroll
    for (int e = 0; e < 4; ++e) {
      pv[e] = __expf(Aval[g * 4 + e] * sd);
      hv[e] = h[g * 4 + e];
    }
    *(float4v*)&P[idx + g * 4] = pv;
    *(float4v*)&Hl[idx + g * 4] = hv;
  }
}

__global__ __launch_bounds__(256) void scan_combine(const float* __restrict__ P,
                                                    const float* __restrict__ Hl,
                                                    float* __restrict__ H0) {
  int idx = blockIdx.x * 256 + threadIdx.x;  // over B*512*16 = 65536
  int b = idx >> 13;
  int ds = idx & 8191;
  float h = 0.f;
#pragma unroll 8
  for (int c = 0; c < NC; ++c) {
    long off = (((long)b * NC + c) << 13) + ds;
    H0[off] = h;
    h = P[off] * h + Hl[off];
  }
}

__global__ __launch_bounds__(256) void scan_pass2(const float* __restrict__ delta,
                                                  u16* __restrict__ yh, u16* __restrict__ yl,
                                                  const u16* __restrict__ xch,
                                                  const u16* __restrict__ xcl,
                                                  const float* __restrict__ bc,
                                                  const float* __restrict__ z,
                                                  const float* __restrict__ A_log,
                                                  const float* __restrict__ Dp,
                                                  const float* __restrict__ H0) {
  int b = blockIdx.z, c = blockIdx.y;
  int tid = threadIdx.x;
  int d = blockIdx.x * 256 + tid;
  __shared__ float sBC[LC][32];
  const long base = (long)b * L_SEQ + (long)c * LC;
  ((float4v*)sBC)[tid] = ((const float4v*)&bc[base * 32])[tid];
  float Aval[16];
  {
    float4v a[4];
#pragma unroll
    for (int g = 0; g < 4; ++g) a[g] = *(const float4v*)&A_log[d * 16 + g * 4];
#pragma unroll
    for (int s = 0; s < 16; ++s) Aval[s] = -__expf(a[s >> 2][s & 3]);
  }
  float Dval = Dp[d];
  float h[16];
  {
    long hidx = (((long)b * NC + c) * 512 + d) * 16;
#pragma unroll
    for (int g = 0; g < 4; ++g) {
      float4v hv = *(const float4v*)&H0[hidx + g * 4];
#pragma unroll
      for (int e = 0; e < 4; ++e) h[g * 4 + e] = hv[e];
    }
  }
  __syncthreads();
#pragma unroll 4
  for (int t = 0; t < LC; ++t) {
    long off = (base + t) * 512 + d;
    float dlv = delta[off];
    float xv = bf2f(xch[off]) + bf2f(xcl[off]);
    float zv = z[off];
    float w = dlv * xv;
    float4v Bv[4], Cv[4];
#pragma unroll
    for (int g = 0; g < 4; ++g) {
      Bv[g] = *(const float4v*)&sBC[t][g * 4];
      Cv[g] = *(const float4v*)&sBC[t][16 + g * 4];
    }
    float ya = 0.f, yb = 0.f, yc2 = 0.f, yd = 0.f;
#pragma unroll
    for (int s = 0; s < 4; ++s) {
      float dA = __expf(dlv * Aval[s]);
      h[s] = dA * h[s] + w * Bv[0][s];
      ya += h[s] * Cv[0][s];
    }
#pragma unroll
    for (int s = 4; s < 8; ++s) {
      float dA = __expf(dlv * Aval[s]);
      h[s] = dA * h[s] + w * Bv[1][s - 4];
      yb += h[s] * Cv[1][s - 4];
    }
#pragma unroll
    for (int s = 8; s < 12; ++s) {
      float dA = __expf(dlv * Aval[s]);
      h[s] = dA * h[s] + w * Bv[2][s - 8];
      yc2 += h[s] * Cv[2][s - 8];
    }
#pragma unroll
    for (int s = 12; s < 16; ++s) {
      float dA = __expf(dlv * Aval[s]);
      h[s] = dA * h[s] + w * Bv[3][s - 12];
      yd += h[s] * Cv[3][s - 12];
    }
    float yv = (ya + yb) + (yc2 + yd);
    float yf = (yv + xv * Dval) * (zv / (1.f + __expf(-zv)));
    u16 hh = f2bf_rn(yf);
    yh[off] = hh;
    yl[off] = f2bf_rn(yf - bf2f(hh));
  }
}

extern "C" void kernel_launch(void* const* d_in, const int* in_sizes, int n_in, void* d_out,
                              int out_size, void* d_ws, size_t ws_size, hipStream_t stream) {
  const float* input = (const float*)d_in[0];
  const float* in_proj_w = (const float*)d_in[1];
  const float* conv_w = (const float*)d_in[2];
  const float* conv_b = (const float*)d_in[3];
  const float* x_proj_w = (const float*)d_in[4];
  const float* dt_proj_w = (const float*)d_in[5];
  const float* dt_proj_b = (const float*)d_in[6];
  const float* A_log = (const float*)d_in[7];
  const float* Dp = (const float*)d_in[8];
  const float* out_proj_w = (const float*)d_in[9];
  const float* out_lin_w = (const float*)d_in[10];
  const float* out_lin_b = (const float*)d_in[11];

  char* ws = (char*)d_ws;
  // x planes: M_ROWS*256 halfs each (8.39 MB); region also hosts H0 (16.78 MB) during scan
  u16* buf_xh = (u16*)(ws);
  u16* buf_xl = (u16*)(ws + 8388608);
  float* buf_xr = (float*)(ws + 16777216);   // 32 MB fp32 (P/Hl alias; then yh/yl)
  float* buf_z = (float*)(ws + 50331648);    // 32 MB fp32
  u16* buf_xch = (u16*)(ws + 83886080);      // 16 MB
  u16* buf_xcl = (u16*)(ws + 100663296);     // 16 MB
  float* buf_bc = (float*)(ws + 117440512);  // 2 MB (M_ROWS x 32)
  u16* buf_wch = (u16*)(ws + 119537664);     // 0.5 MB
  u16* buf_wcl = (u16*)(ws + 120061952);     // 0.5 MB
  float* buf_dy = (float*)(ws + 120586240);  // 32 MB fp32 delta
  u16* buf_wd0h = (u16*)(ws + 154140672);    // 640x512 planes
  u16* buf_wd0l = (u16*)(ws + 154796032);
  u16* buf_wd1h = (u16*)(ws + 155451392);
  u16* buf_wd1l = (u16*)(ws + 156106752);
  u16* buf_wth = (u16*)(ws + 156762112);     // 0.5 MB reusable weight scratch
  u16* buf_wtl = (u16*)(ws + 157286400);
  float* buf_P = buf_xr;                     // 16 MB
  float* buf_Hl = (float*)(ws + 33554432);   // 16 MB
  float* buf_H0 = (float*)ws;                // 16.78 MB (x planes dead during scan)
  u16* buf_yh = (u16*)buf_xr;                // 16 MB (P dead after combine)
  u16* buf_yl = (u16*)(ws + 33554432);       // 16 MB (Hl dead after combine)

  build_wd<<<dim3(2, 640), 256, 0, stream>>>(x_proj_w, dt_proj_w, buf_wd0h, buf_wd0l);
  build_wd<<<dim3(2, 640), 256, 0, stream>>>(x_proj_w + 48 * 512, dt_proj_w + 512 * 16, buf_wd1h,
                                             buf_wd1l);
  build_wcomb<<<dim3(2, 512), 256, 0, stream>>>(out_lin_w, out_proj_w + (long)256 * 512, buf_wch,
                                                buf_wcl);
  transpose_in<<<dim3(64, 8, 8), dim3(32, 8), 0, stream>>>(input, buf_xh, buf_xl);

  for (int i = 0; i < 2; ++i) {
    split_pack<<<1024, 256, 0, stream>>>(in_proj_w + (long)i * 1024 * 256, buf_wth, buf_wtl,
                                         1024 * 256);
    gemm_mfma<3><<<dim3(8, 128), 256, 0, stream>>>(buf_xh, buf_xl, 256, buf_wth, buf_wtl, 256,
                                                   buf_xr, buf_z, nullptr, nullptr, nullptr);
    conv_silu<<<32768, 256, 0, stream>>>(buf_xr, conv_w + i * 512 * 4, conv_b + i * 512, buf_xch,
                                         buf_xcl);
    gemm_mfma<4><<<dim3(5, 128), 256, 0, stream>>>(
        buf_xch, buf_xcl, 512, (i == 0) ? buf_wd0h : buf_wd1h, (i == 0) ? buf_wd0l : buf_wd1l,
        512, buf_dy, buf_bc, nullptr, nullptr, dt_proj_b + i * 512);
    scan_pass1<<<dim3(2, NC, 8), 256, 0, stream>>>(buf_dy, buf_xch, buf_xcl, buf_bc,
                                                   A_log + (long)i * 512 * 16, buf_P, buf_Hl);
    scan_combine<<<256, 256, 0, stream>>>(buf_P, buf_Hl, buf_H0);
    scan_pass2<<<dim3(2, NC, 8), 256, 0, stream>>>(buf_dy, buf_yh, buf_yl, buf_xch, buf_xcl,
                                                   buf_bc, buf_z, A_log + (long)i * 512 * 16,
                                                   Dp + i * 512, buf_H0);
    if (i == 0) {
      split_pack<<<512, 256, 0, stream>>>(out_proj_w, buf_wth, buf_wtl, 256 * 512);
      gemm_mfma<5><<<dim3(2, 128), 256, 0, stream>>>(buf_yh, buf_yl, 512, buf_wth, buf_wtl, 512,
                                                     nullptr, nullptr, buf_xh, buf_xl, nullptr);
    } else {
      gemm_mfma<2><<<dim3(4, 128), 256, 0, stream>>>(buf_yh, buf_yl, 512, buf_wch, buf_wcl, 512,
                                                     (float*)d_out, nullptr, nullptr, nullptr,
                                                     out_lin_b);
    }
  }
}